// Round 13
// baseline (84.668 us; speedup 1.0000x reference)
//
#include <hip/hip_runtime.h>
#include <hip/hip_bf16.h>

#define B 32
#define C 512
#define HW 3136            // 56*56 floats per plane
#define HW4 784            // fx4 per plane
#define TH 0.01f
#define NPG 64             // partial groups (blocks per batch)
#define CPB 8              // channels per block
#define CPW 2              // channels per wave

typedef float fx4 __attribute__((ext_vector_type(4)));

// ---------------------------------------------------------------------------
// Kernel A: barrier-free partial saliency, FULL plane per wave.
// Block = (b, pg) owns 8 channels; each wave independently owns 2 channels.
// Per channel: lane l loads 12 fx4 (cols l+64j) + (l<16) tail fx4 at 768+l
// = whole 784-fx4 plane in the wave; tree-sum + 6-level shfl -> alpha;
// FMA the SAME regs into a 13-fx4 per-wave acc. NO LDS, NO barriers in the
// loop -> waves free-run with 13 loads in flight (R12 showed the barrier
// phase-train was the stall; occupancy was not).
// Epilogue (once): 4 waves dump acc to LDS (50 KB), 1 barrier, 256 threads
// sum 4 regions and store the partial plane contiguously (d_out plane pg).
// __launch_bounds__(256,3): LDS caps at 3 blocks/CU anyway; VGPR headroom
// ~170 so the ~115-reg body cannot spill (R11 lesson).
// ---------------------------------------------------------------------------
__global__ __launch_bounds__(256, 3) void partial_kernel(const float* __restrict__ x,
                                                         float* __restrict__ out) {
    const int b  = blockIdx.y;
    const int pg = blockIdx.x;          // 0..NPG-1
    const int t  = threadIdx.x;
    const int l  = t & 63;
    const int wv = t >> 6;

    __shared__ fx4 lds4[4][HW4];        // 50,176 B

    const fx4* __restrict__ xb = (const fx4*)(x + (size_t)b * C * HW);

    fx4 acc[12];
    fx4 acct = (fx4)0.f;
    #pragma unroll
    for (int j = 0; j < 12; ++j) acc[j] = (fx4)0.f;

    const int cbase = pg * CPB + wv * CPW;
    for (int i = 0; i < CPW; ++i) {
        const fx4* __restrict__ p = xb + (size_t)(cbase + i) * HW4 + l;
        fx4 v[12];
        #pragma unroll
        for (int j = 0; j < 12; ++j) v[j] = p[64 * j];
        fx4 vt = (fx4)0.f;
        if (l < 16) vt = p[768];

        // tree-sum of this lane's 12-13 fx4
        float ps[12];
        #pragma unroll
        for (int j = 0; j < 12; ++j) ps[j] = (v[j].x + v[j].y) + (v[j].z + v[j].w);
        const float pt = (vt.x + vt.y) + (vt.z + vt.w);
        float s = (((ps[0] + ps[1]) + (ps[2] + ps[3])) +
                   ((ps[4] + ps[5]) + (ps[6] + ps[7]))) +
                  (((ps[8] + ps[9]) + (ps[10] + ps[11])) + pt);
        #pragma unroll
        for (int off = 1; off < 64; off <<= 1) s += __shfl_xor(s, off);
        const float a = s * (1.0f / (float)HW);   // alpha[b,c]

        #pragma unroll
        for (int j = 0; j < 12; ++j) acc[j] += v[j] * a;
        acct += vt * a;
    }

    // ---- epilogue: one barrier, cooperative 4-region sum + store ----------
    #pragma unroll
    for (int j = 0; j < 12; ++j) lds4[wv][l + 64 * j] = acc[j];
    if (l < 16) lds4[wv][768 + l] = acct;
    __syncthreads();

    fx4* __restrict__ dst = (fx4*)(out + (size_t)b * C * HW + (size_t)pg * HW);
    {
        fx4 r0 = (lds4[0][t]       + lds4[1][t])       + (lds4[2][t]       + lds4[3][t]);
        fx4 r1 = (lds4[0][t + 256] + lds4[1][t + 256]) + (lds4[2][t + 256] + lds4[3][t + 256]);
        fx4 r2 = (lds4[0][t + 512] + lds4[1][t + 512]) + (lds4[2][t + 512] + lds4[3][t + 512]);
        dst[t]       = r0;
        dst[t + 256] = r1;
        dst[t + 512] = r2;
        if (t < 16) {
            dst[t + 768] = (lds4[0][t + 768] + lds4[1][t + 768]) +
                           (lds4[2][t + 768] + lds4[3][t + 768]);
        }
    }
}

// ---------------------------------------------------------------------------
// Kernel B: sum 64 partials -> sal, then expansion (validated in R11/R12).
// Block = (b, tile of 16 fx4 cols). Partials live in d_out planes co=0..63,
// read before this block overwrites them (read->sync->write within block).
// ---------------------------------------------------------------------------
__global__ __launch_bounds__(256) void out_kernel(const float* __restrict__ w,
                                                  const float* __restrict__ scale_p,
                                                  const float* __restrict__ wf_p,
                                                  float* __restrict__ out) {
    const int b    = blockIdx.y;
    const int tile = blockIdx.x;               // 0..48
    const int t    = threadIdx.x;
    const int hw4  = t & 15;
    const int pg4  = t >> 4;                   // 0..15 -> partials 4*pg4 .. 4*pg4+3
    const int lane = t & 63;
    const int wid  = t >> 6;

    const fx4* __restrict__ P =
        (const fx4*)(out + (size_t)b * C * HW) + tile * 16 + hw4;
    fx4 s = (P[(size_t)(4 * pg4) * HW4]     + P[(size_t)(4 * pg4 + 1) * HW4]) +
            (P[(size_t)(4 * pg4 + 2) * HW4] + P[(size_t)(4 * pg4 + 3) * HW4]);

    // reduce the 4 pg4-groups in this wave (lane deltas 16, 32)
    s.x += __shfl_xor(s.x, 16); s.y += __shfl_xor(s.y, 16);
    s.z += __shfl_xor(s.z, 16); s.w += __shfl_xor(s.w, 16);
    s.x += __shfl_xor(s.x, 32); s.y += __shfl_xor(s.y, 32);
    s.z += __shfl_xor(s.z, 32); s.w += __shfl_xor(s.w, 32);

    __shared__ fx4 red[4][16];
    if (lane < 16) red[wid][lane] = s;
    __syncthreads();

    __shared__ fx4 sal_sm[16];
    if (t < 16) {
        sal_sm[t] = ((red[0][t] + red[1][t]) + (red[2][t] + red[3][t])) *
                    (1.0f / (float)C);
    }
    __syncthreads();

    const float scale = scale_p[0];
    const float wf    = wf_p[0];
    const float out_zero = 1.0f - 0.5f * wf;   // fm == 0 path
    const fx4 s4 = sal_sm[hw4];

    fx4* __restrict__ ob = (fx4*)(out + (size_t)b * C * HW) + tile * 16 + hw4;
    const int c0 = pg4 * 32;                   // each group covers its 32 co's

    #pragma unroll 4
    for (int k = 0; k < 32; ++k) {
        const int co = c0 + k;
        const float wc = w[co];
        fx4 r;
        float fm;
        fm = s4.x * wc;
        r.x = (fm > TH) ? 1.0f - wf / (1.0f + __expf(-scale * fm)) : out_zero;
        fm = s4.y * wc;
        r.y = (fm > TH) ? 1.0f - wf / (1.0f + __expf(-scale * fm)) : out_zero;
        fm = s4.z * wc;
        r.z = (fm > TH) ? 1.0f - wf / (1.0f + __expf(-scale * fm)) : out_zero;
        fm = s4.w * wc;
        r.w = (fm > TH) ? 1.0f - wf / (1.0f + __expf(-scale * fm)) : out_zero;
        __builtin_nontemporal_store(r, ob + (size_t)co * HW4);
    }
}

extern "C" void kernel_launch(void* const* d_in, const int* in_sizes, int n_in,
                              void* d_out, int out_size, void* d_ws, size_t ws_size,
                              hipStream_t stream) {
    const float* x      = (const float*)d_in[0];
    const float* conv_w = (const float*)d_in[1];   // 512 floats
    const float* scale  = (const float*)d_in[2];
    const float* wf     = (const float*)d_in[3];
    float* out = (float*)d_out;

    dim3 gridA(NPG, B);                            // 64 x 32 = 2048 blocks
    partial_kernel<<<gridA, 256, 0, stream>>>(x, out);

    dim3 gridB(HW4 / 16, B);                       // 49 x 32 = 1568 blocks
    out_kernel<<<gridB, 256, 0, stream>>>(conv_w, scale, wf, out);
}